// Round 12
// baseline (1389.513 us; speedup 1.0000x reference)
//
#include <hip/hip_runtime.h>
#include <cmath>

#define VOCAB 32000
#define EMB   256
#define HID   512
#define TLEN  513      // SEQ + 1
#define G4    2048     // 4*HID
#define NBLK  128      // recurrence blocks (1 active wave each, 4 h-elems)
#define SOS   1

typedef unsigned long long u64;
typedef unsigned int uivec4 __attribute__((ext_vector_type(4)));
typedef float f32x4 __attribute__((ext_vector_type(4)));
typedef short bf16x8 __attribute__((ext_vector_type(8)));

__device__ inline float fsig(float x)  { return __builtin_amdgcn_rcpf(1.f + __expf(-x)); }
__device__ inline float ftanh(float x) { return 1.f - 2.f * __builtin_amdgcn_rcpf(__expf(2.f * x) + 1.f); }
__device__ inline float fma4(f32x4 w, f32x4 h, float a) {
    return fmaf(w[0], h[0], fmaf(w[1], h[1], fmaf(w[2], h[2], fmaf(w[3], h[3], a))));
}

// split fp32 -> bf16 hi + bf16 lo (RNE both); x ~= hi + lo to ~2^-18 rel
__device__ inline void bf16split(float f, short& h, short& l) {
    unsigned u = __float_as_uint(f);
    unsigned r = u + (0x7fffu + ((u >> 16) & 1u));
    unsigned hb = r & 0xffff0000u;
    h = (short)(hb >> 16);
    float res = f - __uint_as_float(hb);
    unsigned u2 = __float_as_uint(res);
    unsigned r2 = u2 + (0x7fffu + ((u2 >> 16) & 1u));
    l = (short)(r2 >> 16);
}

// ---------------------------------------------------------------------------
// Fused kernel: 128 blocks x 256 threads, 1 block/CU (exclusive CUs).
// Phase 1 (all 4 waves): this block's Xg slice [513][16] -> LDS.
//   slice row r (0..15) = global gate row (r>>2)*512 + 4*W + (r&3).
// Phase 2 (wave 0 only; waves 1-3 exit): r11-proven recurrence, with
//   xg = ds_read(lds) — NO per-step HBM/vmcnt dependency in the poll path.
// Transport: tag|float u64 single-copy-atomic words via MALL (sc0 sc1 /
// agent atomics) — proven rounds 2-11. Full-h poll per wave preserves the
// slot-reuse invariant; stale cross-replay tags benign (h deterministic).
// ---------------------------------------------------------------------------
__global__ __launch_bounds__(256, 1) void rec_fused(
    const int* __restrict__ seq, const float* __restrict__ emb,
    const float* __restrict__ W_ih, const float* __restrict__ b_ih,
    const float* __restrict__ b_hh, const float* __restrict__ W_hh,
    const float* __restrict__ h0, const float* __restrict__ c0,
    float* __restrict__ hs, u64* pk,
    float* __restrict__ out_hT, float* __restrict__ out_cT)
{
    __shared__ __align__(16) float xg_lds[TLEN * 16];   // 32.8 KB

    const int W   = blockIdx.x;       // 0..127
    const int tid = threadIdx.x;
    const int j4  = 4 * W;

    // ---------------- phase 1: Xg slice -> LDS ----------------
    {
        const int r  = tid & 15;                  // slice row
        const int grow = (r >> 2) * HID + j4 + (r & 3);
        const float bias = b_ih[grow] + b_hh[grow];
        const f32x4* wp = (const f32x4*)(W_ih + (size_t)grow * EMB);
        for (int t = (tid >> 4); t < TLEN; t += 16) {
            int tok = (t == 0) ? SOS : seq[t - 1];
            const f32x4* ep = (const f32x4*)(emb + (size_t)tok * EMB);
            float a0 = 0.f, a1 = 0.f, a2 = 0.f, a3 = 0.f;
#pragma unroll 4
            for (int k = 0; k < EMB / 16; ++k) {
                a0 = fma4(wp[4 * k],     ep[4 * k],     a0);
                a1 = fma4(wp[4 * k + 1], ep[4 * k + 1], a1);
                a2 = fma4(wp[4 * k + 2], ep[4 * k + 2], a2);
                a3 = fma4(wp[4 * k + 3], ep[4 * k + 3], a3);
            }
            xg_lds[t * 16 + r] = ((a0 + a1) + (a2 + a3)) + bias;
        }
    }
    __syncthreads();
    if (tid >= 64) return;            // waves 1-3 done; wave 0 runs recurrence

    // ---------------- phase 2: recurrence (r11 core) ----------------
    const int ln = tid;               // 0..63
    const int qs = (ln >> 2) & 3;     // gate of my reduced row
    const int ds = ln & 3;            // j-offset of my reduced row

    // weights: rows r=4q+d, k-slice [8ln,8ln+8)
    f32x4 wa[16], wb[16];
#pragma unroll
    for (int r = 0; r < 16; ++r) {
        const float* wp = W_hh + ((size_t)(r >> 2) * HID + j4 + (r & 3)) * HID + 8 * ln;
        wa[r] = *(const f32x4*)wp;
        wb[r] = *(const f32x4*)(wp + 4);
    }
#pragma unroll
    for (int r = 0; r < 16; ++r) {
        asm volatile("" : "+v"(wa[r]), "+v"(wb[r]));
    }

    float c = (ln < 4) ? c0[j4 + ln] : 0.f;

    f32x4 hA, hB;                     // my 8 h-values (k-slice [8ln,8ln+8))
    {
        const float* hp = h0 + 8 * ln;
        hA = *(const f32x4*)hp;
        hB = *(const f32x4*)(hp + 4);
    }

    for (int t = 0; t < TLEN; ++t) {
        // Xg from LDS: 16 words, 4-way broadcast, conflict-free; lgkmcnt
        // only — the poll's vmcnt(0) no longer waits on any Xg fetch.
        float xg = xg_lds[t * 16 + (ln & 15)];

        if (t > 0) {
            const unsigned tt = (unsigned)t;
            u64 sa = (u64)(uintptr_t)(pk + (size_t)(t & 1) * HID + 8 * ln);
            uivec4 r0, r1, r2, r3;
            for (;;) {
                asm volatile(
                    "global_load_dwordx4 %0, %4, off sc0 sc1\n\t"
                    "global_load_dwordx4 %1, %4, off offset:16 sc0 sc1\n\t"
                    "global_load_dwordx4 %2, %4, off offset:32 sc0 sc1\n\t"
                    "global_load_dwordx4 %3, %4, off offset:48 sc0 sc1\n\t"
                    "s_waitcnt vmcnt(0)"
                    : "=&v"(r0), "=&v"(r1), "=&v"(r2), "=&v"(r3) : "v"(sa));
                if (r0.y == tt && r0.w == tt && r1.y == tt && r1.w == tt &&
                    r2.y == tt && r2.w == tt && r3.y == tt && r3.w == tt) break;
            }
            hA[0] = __uint_as_float(r0.x); hA[1] = __uint_as_float(r0.z);
            hA[2] = __uint_as_float(r1.x); hA[3] = __uint_as_float(r1.z);
            hB[0] = __uint_as_float(r2.x); hB[1] = __uint_as_float(r2.z);
            hB[2] = __uint_as_float(r3.x); hB[3] = __uint_as_float(r3.z);
        }

        // 16-row partial matvec over my 8 k-cols (registers)
        float p[16];
#pragma unroll
        for (int r = 0; r < 16; ++r)
            p[r] = fma4(wa[r], hA, fma4(wb[r], hB, 0.f));

        // packed butterfly: lane ends up holding row (ln&15) over its
        // 16-lane k-group; xor16+xor32 complete the 512-k sum.
        const bool b0 = (ln & 1), b1 = (ln & 2), b2 = (ln & 4), b3 = (ln & 8);
        float q1[8];
#pragma unroll
        for (int i = 0; i < 8; ++i) {
            float mine = b0 ? p[2*i+1] : p[2*i];
            float send = b0 ? p[2*i]   : p[2*i+1];
            q1[i] = mine + __shfl_xor(send, 1, 64);
        }
        float q2[4];
#pragma unroll
        for (int i = 0; i < 4; ++i) {
            float mine = b1 ? q1[2*i+1] : q1[2*i];
            float send = b1 ? q1[2*i]   : q1[2*i+1];
            q2[i] = mine + __shfl_xor(send, 2, 64);
        }
        float q3[2];
#pragma unroll
        for (int i = 0; i < 2; ++i) {
            float mine = b2 ? q2[2*i+1] : q2[2*i];
            float send = b2 ? q2[2*i]   : q2[2*i+1];
            q3[i] = mine + __shfl_xor(send, 4, 64);
        }
        float q4;
        {
            float mine = b3 ? q3[1] : q3[0];
            float send = b3 ? q3[0] : q3[1];
            q4 = mine + __shfl_xor(send, 8, 64);
        }
        q4 += __shfl_xor(q4, 16, 64);
        q4 += __shfl_xor(q4, 32, 64);
        float gate = q4 + xg;        // lane holds gate row (ln&15): q=qs, d=ds

        float v = (qs == 2) ? ftanh(gate) : fsig(gate);
        float iv = __shfl(v, ds,      64);
        float fv = __shfl(v, 4 + ds,  64);
        float gv = __shfl(v, 8 + ds,  64);
        float ov = __shfl(v, 12 + ds, 64);
        c = fmaf(fv, c, iv * gv);
        float h_ = ov * ftanh(c);

        if (ln < 4) {                // my 4 h-elements: j = 4W + ln
            if (t < TLEN - 1) {
                u64 word = ((u64)(unsigned)(t + 1) << 32) | (u64)__float_as_uint(h_);
                __hip_atomic_store(&pk[(size_t)((t + 1) & 1) * HID + j4 + ln], word,
                                   __ATOMIC_RELAXED, __HIP_MEMORY_SCOPE_AGENT);
            } else {
                out_hT[j4 + ln] = h_;
                out_cT[j4 + ln] = c;
            }
            hs[(size_t)t * HID + j4 + ln] = h_;
        }
    }
}

// ---------------------------------------------------------------------------
// Kernel C: out[t][v] = hs[t].W_out[v] + b_out[v]  via split-bf16 MFMA.
// (proven round 8: x = hi+lo bf16; A.B ~= Ah.Bh + Ah.Bl + Al.Bh, fp32 accum)
// ---------------------------------------------------------------------------
#define GLDT 40

__global__ __launch_bounds__(256, 2) void out_gemm_mfma(
    const float* __restrict__ hs, const float* __restrict__ W_out,
    const float* __restrict__ b_out, float* __restrict__ out)
{
    __shared__ __align__(16) short Ah[128][GLDT];
    __shared__ __align__(16) short Al[128][GLDT];
    __shared__ __align__(16) short Bh[128][GLDT];
    __shared__ __align__(16) short Bl[128][GLDT];

    const int tb = blockIdx.x;     // 0..4   (time tiles)
    const int vb = blockIdx.y;     // 0..249 (vocab tiles)
    const int tid = threadIdx.x;
    const int w   = tid >> 6;      // wave 0..3
    const int l   = tid & 63;
    const int l15 = l & 15;
    const int lg  = l >> 4;
    const int m0 = tb * 128, n0 = vb * 128;

    const int sr = tid >> 1;
    const int kh = (tid & 1) * 16;

    f32x4 acc[2][8];
#pragma unroll
    for (int s = 0; s < 2; ++s)
#pragma unroll
        for (int cc = 0; cc < 8; ++cc) acc[s][cc] = (f32x4){0.f, 0.f, 0.f, 0.f};

    for (int k0 = 0; k0 < HID; k0 += 32) {
        {
            int trow = m0 + sr;
            float4 fa0 = make_float4(0.f,0.f,0.f,0.f), fa1 = fa0, fa2 = fa0, fa3 = fa0;
            if (trow < TLEN) {
                const float4* ap = (const float4*)(hs + (size_t)trow * HID + k0 + kh);
                fa0 = ap[0]; fa1 = ap[1]; fa2 = ap[2]; fa3 = ap[3];
            }
            float fv[16] = { fa0.x,fa0.y,fa0.z,fa0.w, fa1.x,fa1.y,fa1.z,fa1.w,
                             fa2.x,fa2.y,fa2.z,fa2.w, fa3.x,fa3.y,fa3.z,fa3.w };
#pragma unroll
            for (int g = 0; g < 2; ++g) {
                union { short s[8]; bf16x8 v; } ph, pl;
#pragma unroll
                for (int e = 0; e < 8; ++e) bf16split(fv[g * 8 + e], ph.s[e], pl.s[e]);
                *(bf16x8*)&Ah[sr][kh + 8 * g] = ph.v;
                *(bf16x8*)&Al[sr][kh + 8 * g] = pl.v;
            }
        }
        {
            const float4* bp = (const float4*)(W_out + (size_t)(n0 + sr) * HID + k0 + kh);
            float4 fb0 = bp[0], fb1 = bp[1], fb2 = bp[2], fb3 = bp[3];
            float fv[16] = { fb0.x,fb0.y,fb0.z,fb0.w, fb1.x,fb1.y,fb1.z,fb1.w,
                             fb2.x,fb2.y,fb2.z,fb2.w, fb3.x,fb3.y,fb3.z,fb3.w };
#pragma unroll
            for (int g = 0; g < 2; ++g) {
                union { short s[8]; bf16x8 v; } ph, pl;
#pragma unroll
                for (int e = 0; e < 8; ++e) bf16split(fv[g * 8 + e], ph.s[e], pl.s[e]);
                *(bf16x8*)&Bh[sr][kh + 8 * g] = ph.v;
                *(bf16x8*)&Bl[sr][kh + 8 * g] = pl.v;
            }
        }
        __syncthreads();

        bf16x8 ah[2], al2[2];
#pragma unroll
        for (int s = 0; s < 2; ++s) {
            ah[s]  = *(const bf16x8*)&Ah[32 * w + 16 * s + l15][8 * lg];
            al2[s] = *(const bf16x8*)&Al[32 * w + 16 * s + l15][8 * lg];
        }
#pragma unroll
        for (int cc = 0; cc < 8; ++cc) {
            bf16x8 bh = *(const bf16x8*)&Bh[16 * cc + l15][8 * lg];
            bf16x8 bl = *(const bf16x8*)&Bl[16 * cc + l15][8 * lg];
#pragma unroll
            for (int s = 0; s < 2; ++s) {
                acc[s][cc] = __builtin_amdgcn_mfma_f32_16x16x32_bf16(ah[s],  bh, acc[s][cc], 0, 0, 0);
                acc[s][cc] = __builtin_amdgcn_mfma_f32_16x16x32_bf16(ah[s],  bl, acc[s][cc], 0, 0, 0);
                acc[s][cc] = __builtin_amdgcn_mfma_f32_16x16x32_bf16(al2[s], bh, acc[s][cc], 0, 0, 0);
            }
        }
        __syncthreads();
    }

#pragma unroll
    for (int cc = 0; cc < 8; ++cc) {
        int col = n0 + 16 * cc + l15;
        float bo = b_out[col];
#pragma unroll
        for (int s = 0; s < 2; ++s) {
            int rbase = m0 + 32 * w + 16 * s + lg * 4;
#pragma unroll
            for (int r = 0; r < 4; ++r) {
                int trow = rbase + r;
                if (trow < TLEN) out[(size_t)trow * VOCAB + col] = acc[s][cc][r] + bo;
            }
        }
    }
}

// ---------------------------------------------------------------------------
extern "C" void kernel_launch(void* const* d_in, const int* in_sizes, int n_in,
                              void* d_out, int out_size, void* d_ws, size_t ws_size,
                              hipStream_t stream)
{
    const int*   seq   = (const int*)  d_in[0];
    const float* h0    = (const float*)d_in[1];
    const float* c0    = (const float*)d_in[2];
    const float* emb   = (const float*)d_in[3];
    const float* W_ih  = (const float*)d_in[4];
    const float* W_hh  = (const float*)d_in[5];
    const float* b_ih  = (const float*)d_in[6];
    const float* b_hh  = (const float*)d_in[7];
    const float* W_out = (const float*)d_in[8];
    const float* b_out = (const float*)d_in[9];

    float* out_logits = (float*)d_out;                      // [513][32000]
    float* out_hT     = out_logits + (size_t)TLEN * VOCAB;  // [512]
    float* out_cT     = out_hT + HID;                       // [512]

    float* hs = (float*)d_ws;                    // 513*512 f
    u64*   pk = (u64*)(hs + (size_t)TLEN * HID); // [2][512] tag|h MALL words

    hipMemsetAsync(pk, 0, 2 * HID * sizeof(u64), stream);
    rec_fused<<<NBLK, 256, 0, stream>>>(seq, emb, W_ih, b_ih, b_hh, W_hh,
                                        h0, c0, hs, pk, out_hT, out_cT);
    out_gemm_mfma<<<dim3(5, 250), 256, 0, stream>>>(hs, W_out, b_out, out_logits);
}

// Round 14
// 957.439 us; speedup vs baseline: 1.4513x; 1.4513x over previous
//
#include <hip/hip_runtime.h>
#include <cmath>

#define VOCAB 32000
#define EMB   256
#define HID   512
#define TLEN  513      // SEQ + 1
#define G4    2048     // 4*HID
#define NWG   32       // recurrence workgroups
#define SOS   1

typedef unsigned long long u64;
typedef unsigned int uivec4 __attribute__((ext_vector_type(4)));
typedef float f32x4 __attribute__((ext_vector_type(4)));
typedef short bf16x8 __attribute__((ext_vector_type(8)));

__device__ inline float fsig(float x)  { return __builtin_amdgcn_rcpf(1.f + __expf(-x)); }
__device__ inline float ftanh(float x) { return 1.f - 2.f * __builtin_amdgcn_rcpf(__expf(2.f * x) + 1.f); }
__device__ inline float fma4(f32x4 w, f32x4 h, float a) {
    return fmaf(w[0], h[0], fmaf(w[1], h[1], fmaf(w[2], h[2], fmaf(w[3], h[3], a))));
}

// split fp32 -> bf16 hi + bf16 lo (RNE both); x ~= hi + lo to ~2^-18 rel
__device__ inline void bf16split(float f, short& h, short& l) {
    unsigned u = __float_as_uint(f);
    unsigned r = u + (0x7fffu + ((u >> 16) & 1u));
    unsigned hb = r & 0xffff0000u;
    h = (short)(hb >> 16);
    float res = f - __uint_as_float(hb);
    unsigned u2 = __float_as_uint(res);
    unsigned r2 = u2 + (0x7fffu + ((u2 >> 16) & 1u));
    l = (short)(r2 >> 16);
}

// ---------------------------------------------------------------------------
// Kernel A: Xg[t][r] = W_ih[r] . emb[tok_t] + b_ih[r] + b_hh[r]   (proven)
// ---------------------------------------------------------------------------
__global__ __launch_bounds__(256) void precompute_gates(
    const int* __restrict__ seq, const float* __restrict__ emb,
    const float* __restrict__ W_ih, const float* __restrict__ b_ih,
    const float* __restrict__ b_hh, float* __restrict__ Xg)
{
    __shared__ __align__(16) float ebuf[16][EMB];
    const int bt = blockIdx.x;   // 0..32
    const int br = blockIdx.y;   // 0..7
    const int tid = threadIdx.x;

    for (int tt = 0; tt < 16; ++tt) {
        int t = bt * 16 + tt;
        if (t < TLEN) {
            int tok = (t == 0) ? SOS : seq[t - 1];
            ebuf[tt][tid] = emb[(size_t)tok * EMB + tid];
        }
    }
    __syncthreads();

    const int row = br * 256 + tid;
    float acc[16];
#pragma unroll
    for (int tt = 0; tt < 16; ++tt) acc[tt] = 0.f;

    const float4* wp = (const float4*)(W_ih + (size_t)row * EMB);
#pragma unroll 4
    for (int k4 = 0; k4 < EMB / 4; ++k4) {
        float4 w = wp[k4];
#pragma unroll
        for (int tt = 0; tt < 16; ++tt) {
            float4 e = *(const float4*)&ebuf[tt][k4 * 4];
            acc[tt] = fmaf(w.x, e.x, fmaf(w.y, e.y, fmaf(w.z, e.z, fmaf(w.w, e.w, acc[tt]))));
        }
    }

    const float bias = b_ih[row] + b_hh[row];
    for (int tt = 0; tt < 16; ++tt) {
        int t = bt * 16 + tt;
        if (t < TLEN) Xg[(size_t)t * G4 + row] = acc[tt] + bias;
    }
}

// ---------------------------------------------------------------------------
// Kernel B: persistent LSTM recurrence — r10 core, dead fast-path removed.
// 32 blocks x 256 threads; transport = tag|float u64 single-copy-atomic
// words via MALL. PROBE: publish via atomic EXCHANGE (executes AT the
// coherence point -> word is MALL-visible on completion, no lazy L2
// writeback), poll via sc0 sc1 dwordx4 loads (proven). No B1 barrier:
// wave wv polls exactly words [128wv,128wv+128) and its matvec reads only
// that hbuf slice (wave-local, in-order LDS). pbuf double-buffered.
// ---------------------------------------------------------------------------
__global__ __launch_bounds__(256, 1) void lstm_recurrence(
    const float* __restrict__ Xg, const float* __restrict__ W_hh,
    const float* __restrict__ h0, const float* __restrict__ c0,
    float* __restrict__ hs, u64* pk,
    float* __restrict__ out_hT, float* __restrict__ out_cT)
{
    __shared__ __align__(16) float hbuf[HID];
    __shared__ float pbuf[2][256];

    const int wg  = blockIdx.x;     // 0..31
    const int tid = threadIdx.x;
    const int wv  = tid >> 6;       // k segment 0..3
    const int ln  = tid & 63;
    const int q   = ln >> 4;        // gate i,f,g,o
    const int j   = ln & 15;
    const int row = q * HID + wg * 16 + j;

    f32x4 wreg[32];
    const f32x4* wp = (const f32x4*)(W_hh + (size_t)row * HID + wv * 128);
#pragma unroll
    for (int i = 0; i < 32; ++i) wreg[i] = wp[i];

    float c = (tid < 16) ? c0[wg * 16 + tid] : 0.f;
    {
        float2 h2 = *(const float2*)&h0[tid * 2];
        hbuf[tid * 2]     = h2.x;
        hbuf[tid * 2 + 1] = h2.y;
    }
    __syncthreads();

    for (int t = 0; t < TLEN; ++t) {
        // activation lanes' Xg (4 gate rows each), issued before the poll
        float xg0 = 0.f, xg1 = 0.f, xg2 = 0.f, xg3 = 0.f;
        if (tid < 16) {
            const float* xp = Xg + (size_t)t * G4 + wg * 16 + tid;
            xg0 = xp[0]; xg1 = xp[512]; xg2 = xp[1024]; xg3 = xp[1536];
        }

        if (t > 0) {
            const unsigned tt = (unsigned)t;
            u64 sa = (u64)(uintptr_t)(pk + (size_t)(t & 1) * HID + 2 * tid);
            uivec4 r;
            do {
                asm volatile("global_load_dwordx4 %0, %1, off sc0 sc1\n\t"
                             "s_waitcnt vmcnt(0)" : "=v"(r) : "v"(sa));
            } while (r.y != tt || r.w != tt);
            hbuf[2 * tid]     = __uint_as_float(r.x);
            hbuf[2 * tid + 1] = __uint_as_float(r.z);
            asm volatile("s_waitcnt lgkmcnt(0)" ::: "memory");
            // no barrier: this wave wrote exactly the slice it reads below
        }

        // partial matvec (hbuf b128 reads are full-wave broadcasts: conflict-free)
        float a0 = 0.f, a1 = 0.f, a2 = 0.f, a3 = 0.f;
        float a4 = 0.f, a5 = 0.f, a6 = 0.f, a7 = 0.f;
        const f32x4* hp = (const f32x4*)&hbuf[wv * 128];
#pragma unroll
        for (int i = 0; i < 32; i += 8) {
            a0 = fma4(wreg[i],     hp[i],     a0);
            a1 = fma4(wreg[i + 1], hp[i + 1], a1);
            a2 = fma4(wreg[i + 2], hp[i + 2], a2);
            a3 = fma4(wreg[i + 3], hp[i + 3], a3);
            a4 = fma4(wreg[i + 4], hp[i + 4], a4);
            a5 = fma4(wreg[i + 5], hp[i + 5], a5);
            a6 = fma4(wreg[i + 6], hp[i + 6], a6);
            a7 = fma4(wreg[i + 7], hp[i + 7], a7);
        }
        pbuf[t & 1][tid] = ((a0 + a1) + (a2 + a3)) + ((a4 + a5) + (a6 + a7));
        __syncthreads();                                  // the step's ONLY barrier

        if (tid < 16) {
            const float* pb = pbuf[t & 1];
            float gi = pb[tid]      + pb[64 + tid]  + pb[128 + tid] + pb[192 + tid] + xg0;
            float gf = pb[16 + tid] + pb[80 + tid]  + pb[144 + tid] + pb[208 + tid] + xg1;
            float gg = pb[32 + tid] + pb[96 + tid]  + pb[160 + tid] + pb[224 + tid] + xg2;
            float go = pb[48 + tid] + pb[112 + tid] + pb[176 + tid] + pb[240 + tid] + xg3;
            float i_ = fsig(gi);
            float f_ = fsig(gf);
            float g_ = ftanh(gg);
            float o_ = fsig(go);
            c = fmaf(f_, c, i_ * g_);
            float h_ = o_ * ftanh(c);
            if (t < TLEN - 1) {
                // PROBE: atomic exchange publishes AT the MALL (no lazy
                // writeback); result unused; word still single-copy atomic.
                u64 word = ((u64)(unsigned)(t + 1) << 32) | (u64)__float_as_uint(h_);
                (void)__hip_atomic_exchange(
                    &pk[(size_t)((t + 1) & 1) * HID + wg * 16 + tid], word,
                    __ATOMIC_RELAXED, __HIP_MEMORY_SCOPE_AGENT);
            } else {
                out_hT[wg * 16 + tid] = h_;
                out_cT[wg * 16 + tid] = c;
            }
            hs[(size_t)t * HID + wg * 16 + tid] = h_;
        }
        // pbuf hazard handled by double-buffer: step t+1 writes pbuf[(t+1)&1].
    }
}

// ---------------------------------------------------------------------------
// Kernel C: out[t][v] = hs[t].W_out[v] + b_out[v]  via split-bf16 MFMA.
// (proven round 8: x = hi+lo bf16; A.B ~= Ah.Bh + Ah.Bl + Al.Bh, fp32 accum)
// ---------------------------------------------------------------------------
#define GLDT 40

__global__ __launch_bounds__(256, 2) void out_gemm_mfma(
    const float* __restrict__ hs, const float* __restrict__ W_out,
    const float* __restrict__ b_out, float* __restrict__ out)
{
    __shared__ __align__(16) short Ah[128][GLDT];
    __shared__ __align__(16) short Al[128][GLDT];
    __shared__ __align__(16) short Bh[128][GLDT];
    __shared__ __align__(16) short Bl[128][GLDT];

    const int tb = blockIdx.x;     // 0..4   (time tiles)
    const int vb = blockIdx.y;     // 0..249 (vocab tiles)
    const int tid = threadIdx.x;
    const int w   = tid >> 6;      // wave 0..3
    const int l   = tid & 63;
    const int l15 = l & 15;
    const int lg  = l >> 4;
    const int m0 = tb * 128, n0 = vb * 128;

    const int sr = tid >> 1;
    const int kh = (tid & 1) * 16;

    f32x4 acc[2][8];
#pragma unroll
    for (int s = 0; s < 2; ++s)
#pragma unroll
        for (int cc = 0; cc < 8; ++cc) acc[s][cc] = (f32x4){0.f, 0.f, 0.f, 0.f};

    for (int k0 = 0; k0 < HID; k0 += 32) {
        {
            int trow = m0 + sr;
            float4 fa0 = make_float4(0.f,0.f,0.f,0.f), fa1 = fa0, fa2 = fa0, fa3 = fa0;
            if (trow < TLEN) {
                const float4* ap = (const float4*)(hs + (size_t)trow * HID + k0 + kh);
                fa0 = ap[0]; fa1 = ap[1]; fa2 = ap[2]; fa3 = ap[3];
            }
            float fv[16] = { fa0.x,fa0.y,fa0.z,fa0.w, fa1.x,fa1.y,fa1.z,fa1.w,
                             fa2.x,fa2.y,fa2.z,fa2.w, fa3.x,fa3.y,fa3.z,fa3.w };
#pragma unroll
            for (int g = 0; g < 2; ++g) {
                union { short s[8]; bf16x8 v; } ph, pl;
#pragma unroll
                for (int e = 0; e < 8; ++e) bf16split(fv[g * 8 + e], ph.s[e], pl.s[e]);
                *(bf16x8*)&Ah[sr][kh + 8 * g] = ph.v;
                *(bf16x8*)&Al[sr][kh + 8 * g] = pl.v;
            }
        }
        {
            const float4* bp = (const float4*)(W_out + (size_t)(n0 + sr) * HID + k0 + kh);
            float4 fb0 = bp[0], fb1 = bp[1], fb2 = bp[2], fb3 = bp[3];
            float fv[16] = { fb0.x,fb0.y,fb0.z,fb0.w, fb1.x,fb1.y,fb1.z,fb1.w,
                             fb2.x,fb2.y,fb2.z,fb2.w, fb3.x,fb3.y,fb3.z,fb3.w };
#pragma unroll
            for (int g = 0; g < 2; ++g) {
                union { short s[8]; bf16x8 v; } ph, pl;
#pragma unroll
                for (int e = 0; e < 8; ++e) bf16split(fv[g * 8 + e], ph.s[e], pl.s[e]);
                *(bf16x8*)&Bh[sr][kh + 8 * g] = ph.v;
                *(bf16x8*)&Bl[sr][kh + 8 * g] = pl.v;
            }
        }
        __syncthreads();

        bf16x8 ah[2], al2[2];
#pragma unroll
        for (int s = 0; s < 2; ++s) {
            ah[s]  = *(const bf16x8*)&Ah[32 * w + 16 * s + l15][8 * lg];
            al2[s] = *(const bf16x8*)&Al[32 * w + 16 * s + l15][8 * lg];
        }
#pragma unroll
        for (int cc = 0; cc < 8; ++cc) {
            bf16x8 bh = *(const bf16x8*)&Bh[16 * cc + l15][8 * lg];
            bf16x8 bl = *(const bf16x8*)&Bl[16 * cc + l15][8 * lg];
#pragma unroll
            for (int s = 0; s < 2; ++s) {
                acc[s][cc] = __builtin_amdgcn_mfma_f32_16x16x32_bf16(ah[s],  bh, acc[s][cc], 0, 0, 0);
                acc[s][cc] = __builtin_amdgcn_mfma_f32_16x16x32_bf16(ah[s],  bl, acc[s][cc], 0, 0, 0);
                acc[s][cc] = __builtin_amdgcn_mfma_f32_16x16x32_bf16(al2[s], bh, acc[s][cc], 0, 0, 0);
            }
        }
        __syncthreads();
    }

#pragma unroll
    for (int cc = 0; cc < 8; ++cc) {
        int col = n0 + 16 * cc + l15;
        float bo = b_out[col];
#pragma unroll
        for (int s = 0; s < 2; ++s) {
            int rbase = m0 + 32 * w + 16 * s + lg * 4;
#pragma unroll
            for (int r = 0; r < 4; ++r) {
                int trow = rbase + r;
                if (trow < TLEN) out[(size_t)trow * VOCAB + col] = acc[s][cc][r] + bo;
            }
        }
    }
}

// ---------------------------------------------------------------------------
extern "C" void kernel_launch(void* const* d_in, const int* in_sizes, int n_in,
                              void* d_out, int out_size, void* d_ws, size_t ws_size,
                              hipStream_t stream)
{
    const int*   seq   = (const int*)  d_in[0];
    const float* h0    = (const float*)d_in[1];
    const float* c0    = (const float*)d_in[2];
    const float* emb   = (const float*)d_in[3];
    const float* W_ih  = (const float*)d_in[4];
    const float* W_hh  = (const float*)d_in[5];
    const float* b_ih  = (const float*)d_in[6];
    const float* b_hh  = (const float*)d_in[7];
    const float* W_out = (const float*)d_in[8];
    const float* b_out = (const float*)d_in[9];

    float* out_logits = (float*)d_out;                      // [513][32000]
    float* out_hT     = out_logits + (size_t)TLEN * VOCAB;  // [512]
    float* out_cT     = out_hT + HID;                       // [512]

    float* Xg = (float*)d_ws;                    // 513*2048 f
    float* hs = Xg + (size_t)TLEN * G4;          // 513*512 f
    u64*   pk = (u64*)(hs + (size_t)TLEN * HID); // [2][512] tag|h MALL words

    (void)hipMemsetAsync(pk, 0, 2 * HID * sizeof(u64), stream);
    precompute_gates<<<dim3(33, 8), 256, 0, stream>>>(seq, emb, W_ih, b_ih, b_hh, Xg);
    lstm_recurrence<<<NWG, 256, 0, stream>>>(Xg, W_hh, h0, c0, hs, pk, out_hT, out_cT);
    out_gemm_mfma<<<dim3(5, 250), 256, 0, stream>>>(hs, W_out, b_out, out_logits);
}